// Round 6
// baseline (8094.560 us; speedup 1.0000x reference)
//
#include <hip/hip_runtime.h>

// Barrier-free persistent LSTM autoencoder.
// A-frags: global->register direct (no LDS staging, no __syncthreads in step loop)
// B-frags: registers (h-part) + read-only LDS (enc x-part)
// gate exchange: wave-local LDS transpose (lgkmcnt only)
// sync: per-WAVE flags, release/acquire, agent scope

#define Bsz 512
#define Tsz 128
#define Esz 256
#define Hsz 512
#define Zsz 256
#define NG  2048   // 4*Hsz gate columns, interleaved n = 4*j + gate

typedef _Float16 f16;
typedef unsigned long long ull;
typedef __attribute__((ext_vector_type(8))) _Float16 f16x8;
typedef __attribute__((ext_vector_type(4))) float f32x4;
typedef __attribute__((ext_vector_type(4))) int i32x4;

__device__ __forceinline__ float sigm(float x) { return 1.0f / (1.0f + __expf(-x)); }
__device__ __forceinline__ float tanh_f(float x) { return __builtin_fmaf(2.f, sigm(2.f * x), -1.f); }
// 8-f16-granule swizzle within 64-col tiles (bits 3..5 ^= row&7) — involution
__device__ __forceinline__ int swz(int kd, int r) {
    return (kd & ~56) | ((((kd >> 3) & 7) ^ (r & 7)) << 3);
}

__device__ __forceinline__ void gld16(const void* g, void* l) {
    __builtin_amdgcn_global_load_lds(
        (const __attribute__((address_space(1))) unsigned*)g,
        (__attribute__((address_space(3))) unsigned*)l, 16, 0, 0);
}
__device__ __forceinline__ ull ldA(const void* p) {
    return __hip_atomic_load((const ull*)p, __ATOMIC_RELAXED, __HIP_MEMORY_SCOPE_AGENT);
}
__device__ __forceinline__ void stA(void* p, ull v) {
    __hip_atomic_store((ull*)p, v, __ATOMIC_RELAXED, __HIP_MEMORY_SCOPE_AGENT);
}
__device__ __forceinline__ f16x8 mkfrag(ull a, ull b) {
    union { ull u[2]; f16x8 v; } x; x.u[0] = a; x.u[1] = b; return x.v;
}
__device__ __forceinline__ f16x8 asfrag(i32x4 a) {
    union { i32x4 u; f16x8 v; } x; x.u = a; return x.v;
}

// ---------------------------------------------------------------------------
// prep: x -> fp16 (plain); weights -> fp16 gate-interleaved (plain for reg
// path, swizzled for LDS paths); bias folding; h0; zero flags.
// ---------------------------------------------------------------------------
__global__ __launch_bounds__(256) void prep_kernel(
    const float* __restrict__ x,
    const float* __restrict__ enc_W_ih, const float* __restrict__ enc_W_hh,
    const float* __restrict__ enc_b_ih, const float* __restrict__ enc_b_hh,
    const float* __restrict__ dec_W_ih, const float* __restrict__ dec_W_hh,
    const float* __restrict__ dec_b_ih, const float* __restrict__ dec_b_hh,
    const float* __restrict__ z_W,
    f16* __restrict__ x16,   f16* __restrict__ eih_s, f16* __restrict__ ehh_p,
    f16* __restrict__ dhh_p, f16* __restrict__ wsm_p, f16* __restrict__ zw_s,
    float* __restrict__ encB, float* __restrict__ decB, float* __restrict__ decB0,
    f16* __restrict__ hb0, unsigned* __restrict__ flags)
{
    const int tid = blockIdx.x * 256 + threadIdx.x;   // 512 blocks
    const int NT  = 512 * 256;

    for (int i = tid; i < 32768; i += NT) flags[i] = 0;
    for (int i = tid; i < Bsz * Hsz; i += NT) hb0[i] = (f16)0.1f;

    // x16 = (f16)x, same [B][T][E] layout, vectorized
    for (int i = tid; i < (Bsz * Tsz * Esz) / 4; i += NT) {
        const float4 v = *(const float4*)(x + 4 * (size_t)i);
        f16 o[4] = {(f16)v.x, (f16)v.y, (f16)v.z, (f16)v.w};
        ull pk; __builtin_memcpy(&pk, o, 8);
        *(ull*)&x16[4 * (size_t)i] = pk;
    }
    // enc W_ih: [NG][E], SWIZZLED (LDS path)
    for (int i = tid; i < NG * Esz; i += NT) {
        const int n = i >> 8, kd = i & 255;
        const int sr = (n & 3) * Hsz + (n >> 2);
        eih_s[i] = (f16)enc_W_ih[sr * Esz + swz(kd, n)];
    }
    // enc W_hh, dec W_hh, Wsum: [NG][H], PLAIN (register path)
    for (int i = tid; i < NG * Hsz; i += NT) {
        const int n = i >> 9, k = i & 511;
        const int sr = (n & 3) * Hsz + (n >> 2);
        ehh_p[i] = (f16)enc_W_hh[sr * Hsz + k];
        const float dv = dec_W_hh[sr * Hsz + k];
        dhh_p[i] = (f16)dv;
        wsm_p[i] = (f16)(dec_W_ih[sr * Hsz + k] + dv);
    }
    // z_W: [Z][H], SWIZZLED (z_final LDS path)
    for (int i = tid; i < Zsz * Hsz; i += NT) {
        const int n = i >> 9, kd = i & 511;
        zw_s[i] = (f16)z_W[n * Hsz + swz(kd, n)];
    }

    const int wave = tid >> 6, lane = tid & 63;   // 2048 waves exactly
    if (wave < NG) {
        const int sr = (wave & 3) * Hsz + (wave >> 2);
        float s = 0.f;
        for (int k = lane; k < Hsz; k += 64) s += dec_W_ih[sr * Hsz + k];
        for (int off = 32; off; off >>= 1) s += __shfl_down(s, off);
        if (lane == 0) {
            encB[wave] = enc_b_ih[sr] + enc_b_hh[sr];
            const float bi = dec_b_ih[sr] + dec_b_hh[sr];
            decB[wave]  = bi;
            decB0[wave] = bi + 0.1f * s;
        }
    }
}

// ---------------------------------------------------------------------------
// Persistent phase. 256 blocks; group bx=bid&7 owns rows [bx*64,+64);
// ny=bid>>3 owns gate cols [ny*64,+64). 4 waves/block, fully independent
// after init: per-WAVE flags, no block barriers in the step loop.
// ---------------------------------------------------------------------------
template <bool ENC>
__global__ __launch_bounds__(256, 1) void persist_kernel(
    const f16* __restrict__ x16,     // [B][T][E] plain        (ENC)
    const f16* __restrict__ WihS,    // [NG][E] swizzled       (ENC)
    const f16* __restrict__ Whh,     // [NG][H] plain (ehh/dhh)
    const f16* __restrict__ Wsm,     // [NG][H] plain          (DEC)
    const float* __restrict__ biasA, const float* __restrict__ biasB,
    f16* __restrict__ hb0, f16* __restrict__ hb1,
    float* __restrict__ cbuf, f16* __restrict__ Hall,
    unsigned* __restrict__ flags)    // [8][128][16] u32
{
    __shared__ __align__(16) f16 Wih[ENC ? 4 * 4096 : 8];
    __shared__ __align__(16) float xch[4][16][17];
    __shared__ __align__(16) f16 hx[4][32][8];

    const int tid = threadIdx.x, bid = blockIdx.x;
    const int bx = bid & 7, ny = bid >> 3;
    const int b0 = bx * 64, n0 = ny * 64;
    const int lane = tid & 63, w = tid >> 6;
    const int lr = lane & 15, lkb = lane >> 4;
    const int wm = (w & 1) * 32, wn = (w >> 1) * 32;

    // ---- one-time init: enc x-weights -> LDS; h-weights -> registers ----
    if (ENC) {
        const int rl = lane >> 3, kc = (lane & 7) * 8;
#pragma unroll
        for (int kt = 0; kt < 4; ++kt)
#pragma unroll
            for (int s = 0; s < 2; ++s) {
                const int g = w + s * 4, row = g * 8 + rl;
                gld16(WihS + (size_t)(n0 + row) * Esz + kt * 64 + kc,
                      &Wih[kt * 4096 + g * 512]);
            }
    }
    f16x8 bfr[16][2];
#pragma unroll
    for (int s = 0; s < 16; ++s)
#pragma unroll
        for (int j = 0; j < 2; ++j)
            bfr[s][j] = *(const f16x8*)&Whh[(size_t)(n0 + wn + j * 16 + lr) * Hsz + s * 32 + lkb * 8];

    float bvA[2], bvB[2];
#pragma unroll
    for (int j = 0; j < 2; ++j) {
        bvA[j] = biasA[n0 + wn + j * 16 + lr];
        bvB[j] = ENC ? 0.f : biasB[n0 + wn + j * 16 + lr];
    }
    // c ownership: (row = b0+wm+i*16+(lane&15), jcol = (n0+wn+j*16)/4 + (lane>>4))
    float c_frag[2][2];
#pragma unroll
    for (int i = 0; i < 2; ++i)
#pragma unroll
        for (int j = 0; j < 2; ++j)
            c_frag[i][j] = ENC ? 0.1f
                : cbuf[(size_t)(b0 + wm + i * 16 + lr) * Hsz + ((n0 + wn + j * 16) >> 2) + lkb];

    if (ENC) {  // Wih staging visible to all waves
        asm volatile("s_waitcnt vmcnt(0)" ::: "memory");
        __syncthreads();
    }

    unsigned* gf   = flags + bx * (128 * 16);
    unsigned* self = gf + (ny * 4 + w) * 16;
    // each lane polls ONE producer-wave flag (the 64 producing our row half)
    const unsigned* myf = gf + (((lane >> 1) * 4 + (w & 1) + ((lane & 1) << 1)) * 16);

    float* xc = &xch[w][0][0];
    f16*  hxw = &hx[w][0][0];

    for (int t = 0; t < Tsz; ++t) {
        const f16* hsrc = (t & 1) ? hb1 : hb0;
        f16*       hdst = (t & 1) ? hb0 : hb1;

        // ---- enc: issue x A-frags before the wait (independent of h) ----
        i32x4 ax[2][8];
        if (ENC) {
#pragma unroll
            for (int i = 0; i < 2; ++i)
#pragma unroll
                for (int s = 0; s < 8; ++s)
                    ax[i][s] = *(const i32x4*)(x16 +
                        ((size_t)(b0 + wm + i * 16 + lr) * Tsz + t) * Esz + s * 32 + lkb * 8);
        }

        // ---- wait for previous step's producers (per-lane flag poll) ----
        if (t > 0) {
            const unsigned tgt = (unsigned)t;
            while (__hip_atomic_load(myf, __ATOMIC_RELAXED, __HIP_MEMORY_SCOPE_AGENT) < tgt)
                __builtin_amdgcn_s_sleep(2);
            (void)__hip_atomic_load(myf, __ATOMIC_ACQUIRE, __HIP_MEMORY_SCOPE_AGENT);
            asm volatile("" ::: "memory");
        }

        // ---- h A-frags: global -> registers (agent scope, all 16 slices) ----
        ull ah[2][16][2];
#pragma unroll
        for (int i = 0; i < 2; ++i)
#pragma unroll
            for (int s = 0; s < 16; ++s) {
                const f16* p = hsrc + (size_t)(b0 + wm + i * 16 + lr) * Hsz + s * 32 + lkb * 8;
                ah[i][s][0] = ldA(p);
                ah[i][s][1] = ldA(p + 4);
            }

        f32x4 acc[2][2];
#pragma unroll
        for (int j = 0; j < 2; ++j) {
            const float bv = (!ENC && t == 0) ? bvB[j] : bvA[j];
            acc[0][j] = (f32x4){bv, bv, bv, bv};
            acc[1][j] = acc[0][j];
        }

        // ---- MFMA: x-part (enc) then h-part; no barriers ----
        if (ENC) {
#pragma unroll
            for (int s = 0; s < 8; ++s) {
                f16x8 bq[2];
#pragma unroll
                for (int j = 0; j < 2; ++j) {
                    const int rb = wn + j * 16 + lr;
                    bq[j] = *(const f16x8*)&Wih[(s >> 1) * 4096 + rb * 64 +
                                                ((((s & 1) * 4 + lkb) ^ (rb & 7)) * 8)];
                }
#pragma unroll
                for (int i = 0; i < 2; ++i)
#pragma unroll
                    for (int j = 0; j < 2; ++j)
                        acc[i][j] = __builtin_amdgcn_mfma_f32_16x16x32_f16(
                            asfrag(ax[i][s]), bq[j], acc[i][j], 0, 0, 0);
            }
        }
#pragma unroll
        for (int s = 0; s < 16; ++s)
#pragma unroll
            for (int i = 0; i < 2; ++i) {
                const f16x8 af = mkfrag(ah[i][s][0], ah[i][s][1]);
#pragma unroll
                for (int j = 0; j < 2; ++j)
                    acc[i][j] = __builtin_amdgcn_mfma_f32_16x16x32_f16(
                        af, bfr[s][j], acc[i][j], 0, 0, 0);
            }

        // ---- wave-local gate transpose + LSTM elementwise (no barriers) ----
#pragma unroll
        for (int i = 0; i < 2; ++i)
#pragma unroll
            for (int j = 0; j < 2; ++j) {
#pragma unroll
                for (int r = 0; r < 4; ++r)
                    xc[(lane & 15) * 17 + lkb * 4 + r] = acc[i][j][r];
                asm volatile("s_waitcnt lgkmcnt(0)" ::: "memory");
                const float gi = xc[(4 * lkb + 0) * 17 + lr];
                const float gf = xc[(4 * lkb + 1) * 17 + lr];
                const float gg = xc[(4 * lkb + 2) * 17 + lr];
                const float go = xc[(4 * lkb + 3) * 17 + lr];
                asm volatile("s_waitcnt lgkmcnt(0)" ::: "memory");
                const float iv = sigm(gi), fv = sigm(gf);
                const float gv = tanh_f(gg), ov = sigm(go);
                const float cn = fv * c_frag[i][j] + iv * gv;
                c_frag[i][j] = cn;
                hxw[(i * 16 + lr) * 8 + j * 4 + lkb] = (f16)(ov * tanh_f(cn));
            }
        asm volatile("s_waitcnt lgkmcnt(0)" ::: "memory");

        // ---- pack + h store (16B per lane, lanes 0..31) ----
        ull lo = 0, hi = 0;
        const int hrow = b0 + wm + (lane & 31);
        const int cb = (n0 + wn) >> 2;   // 8-col base in H space
        if (lane < 32) {
            lo = *(const ull*)&hxw[lane * 8];
            hi = *(const ull*)&hxw[lane * 8 + 4];
            f16* dp = hdst + (size_t)hrow * Hsz + cb;
            stA(dp, lo);
            stA(dp + 4, hi);
        }

        // ---- drain own stores, signal own flag ----
        asm volatile("s_waitcnt vmcnt(0)" ::: "memory");
        if (t < Tsz - 1 && lane == 0)
            __hip_atomic_store(self, (unsigned)(t + 1),
                               __ATOMIC_RELEASE, __HIP_MEMORY_SCOPE_AGENT);

        if (!ENC) {
            if (lane < 32) {   // Hall (plain, swizzled col granule for z_final)
                f16* hp = Hall + ((size_t)hrow * Tsz + t) * Hsz + swz(cb, t);
                *(ull*)hp = lo;
                *(ull*)(hp + 4) = hi;
            }
            if (t == 0) {      // switch to Wsum weights after step 0
#pragma unroll
                for (int s = 0; s < 16; ++s)
#pragma unroll
                    for (int j = 0; j < 2; ++j)
                        bfr[s][j] = *(const f16x8*)&Wsm[
                            (size_t)(n0 + wn + j * 16 + lr) * Hsz + s * 32 + lkb * 8];
            }
        }
    }

    if (ENC) {   // hand c to the decoder
#pragma unroll
        for (int i = 0; i < 2; ++i)
#pragma unroll
            for (int j = 0; j < 2; ++j)
                cbuf[(size_t)(b0 + wm + i * 16 + lr) * Hsz + ((n0 + wn + j * 16) >> 2) + lkb]
                    = c_frag[i][j];
    }
}

// ---------------------------------------------------------------------------
// final z projection: out[m][col] = tanh(Hall[m] @ zW^T + zb), m = b*T + t
// ---------------------------------------------------------------------------
__global__ __launch_bounds__(256, 2) void z_final(
    const f16* __restrict__ Hall, const f16* __restrict__ zw,
    const float* __restrict__ zb, float* __restrict__ out)
{
    __shared__ f16 As[2][4096];
    __shared__ f16 Bs[2][4096];

    const int tid = threadIdx.x;
    const int lane = tid & 63, w = tid >> 6;
    const int lr = lane & 15, lkb = lane >> 4;
    const int wm = (w & 1) * 32, wn = (w >> 1) * 32;
    const int m0 = blockIdx.x * 64;
    const int n0 = blockIdx.y * 64;
    const int rl = lane >> 3, kc = (lane & 7) * 8;

    f32x4 acc[2][2];
#pragma unroll
    for (int j = 0; j < 2; ++j) {
        const float bv = zb[n0 + wn + j * 16 + lr];
        acc[0][j] = (f32x4){bv, bv, bv, bv};
        acc[1][j] = acc[0][j];
    }

    auto stage = [&](int buf, int kt) {
#pragma unroll
        for (int s = 0; s < 2; ++s) {
            const int g = w + s * 4, row = g * 8 + rl;
            gld16(Hall + (size_t)(m0 + row) * Hsz + kt * 64 + kc, &As[buf][g * 512]);
            gld16(zw   + (size_t)(n0 + row) * Hsz + kt * 64 + kc, &Bs[buf][g * 512]);
        }
    };

    stage(0, 0);
    int cur = 0;
    for (int kt = 0; kt < 8; ++kt) {
        asm volatile("s_waitcnt vmcnt(0)" ::: "memory");
        __syncthreads();
        if (kt + 1 < 8) stage(cur ^ 1, kt + 1);
        f16x8 af[2][2], bf[2][2];
#pragma unroll
        for (int i = 0; i < 2; ++i) {
            const int ra = wm + i * 16 + lr;
            const int rb = wn + i * 16 + lr;
#pragma unroll
            for (int ks = 0; ks < 2; ++ks) {
                af[i][ks] = *(const f16x8*)&As[cur][ra * 64 + (((ks * 4 + lkb) ^ (ra & 7)) * 8)];
                bf[i][ks] = *(const f16x8*)&Bs[cur][rb * 64 + (((ks * 4 + lkb) ^ (rb & 7)) * 8)];
            }
        }
#pragma unroll
        for (int ks = 0; ks < 2; ++ks)
#pragma unroll
            for (int i = 0; i < 2; ++i)
#pragma unroll
                for (int j = 0; j < 2; ++j)
                    acc[i][j] = __builtin_amdgcn_mfma_f32_16x16x32_f16(
                        af[i][ks], bf[j][ks], acc[i][j], 0, 0, 0);
        cur ^= 1;
    }
#pragma unroll
    for (int i = 0; i < 2; ++i)
#pragma unroll
        for (int j = 0; j < 2; ++j)
#pragma unroll
            for (int r = 0; r < 4; ++r) {
                const int m = m0 + wm + i * 16 + lkb * 4 + r;
                const int col = n0 + wn + j * 16 + lr;
                out[(size_t)m * Zsz + col] = tanh_f(acc[i][j][r]);
            }
}

// ---------------------------------------------------------------------------
extern "C" void kernel_launch(void* const* d_in, const int* in_sizes, int n_in,
                              void* d_out, int out_size, void* d_ws, size_t ws_size,
                              hipStream_t stream) {
    (void)in_sizes; (void)n_in; (void)out_size; (void)ws_size;
    const float* x        = (const float*)d_in[0];
    const float* enc_W_ih = (const float*)d_in[1];
    const float* enc_W_hh = (const float*)d_in[2];
    const float* enc_b_ih = (const float*)d_in[3];
    const float* enc_b_hh = (const float*)d_in[4];
    const float* dec_W_ih = (const float*)d_in[5];
    const float* dec_W_hh = (const float*)d_in[6];
    const float* dec_b_ih = (const float*)d_in[7];
    const float* dec_b_hh = (const float*)d_in[8];
    const float* z_W      = (const float*)d_in[9];
    const float* z_b      = (const float*)d_in[10];
    float* out = (float*)d_out;

    unsigned* flags = (unsigned*)d_ws;               // 32768 u32: enc [0..16383], dec [16384..]
    float* fp    = (float*)(flags + 32768);
    float* encB  = fp;  fp += NG;
    float* decB  = fp;  fp += NG;
    float* decB0 = fp;  fp += NG;
    float* cbuf  = fp;  fp += Bsz * Hsz;
    f16* hp    = (f16*)fp;
    f16* hb0   = hp;  hp += Bsz * Hsz;
    f16* hb1   = hp;  hp += Bsz * Hsz;
    f16* x16   = hp;  hp += (size_t)Bsz * Tsz * Esz;
    f16* eih_s = hp;  hp += (size_t)NG * Esz;
    f16* ehh_p = hp;  hp += (size_t)NG * Hsz;
    f16* dhh_p = hp;  hp += (size_t)NG * Hsz;
    f16* wsm_p = hp;  hp += (size_t)NG * Hsz;
    f16* zw_s  = hp;  hp += (size_t)Zsz * Hsz;
    f16* Hall  = hp;  hp += (size_t)Bsz * Tsz * Hsz;

    prep_kernel<<<512, 256, 0, stream>>>(
        x, enc_W_ih, enc_W_hh, enc_b_ih, enc_b_hh,
        dec_W_ih, dec_W_hh, dec_b_ih, dec_b_hh, z_W,
        x16, eih_s, ehh_p, dhh_p, wsm_p, zw_s,
        encB, decB, decB0, hb0, flags);

    persist_kernel<true><<<256, 256, 0, stream>>>(
        x16, eih_s, ehh_p, nullptr, encB, nullptr,
        hb0, hb1, cbuf, nullptr, flags);

    persist_kernel<false><<<256, 256, 0, stream>>>(
        nullptr, nullptr, dhh_p, wsm_p, decB, decB0,
        hb0, hb1, cbuf, Hall, flags + 16384);

    z_final<<<dim3(1024, 4), 256, 0, stream>>>(Hall, zw_s, z_b, out);
}

// Round 7
// 2881.561 us; speedup vs baseline: 2.8091x; 2.8091x over previous
//
#include <hip/hip_runtime.h>

// Barrier-free persistent LSTM autoencoder, R7.
// A-frags: global->register direct; B-frags: read-only LDS (loaded once).
// No __syncthreads / no acquire-release in the 128-step loop.
// Sync: per-wave relaxed flags + explicit vmcnt drains.

#define Bsz 512
#define Tsz 128
#define Esz 256
#define Hsz 512
#define Zsz 256
#define NG  2048   // 4*Hsz gate columns, interleaved n = 4*j + gate

typedef _Float16 f16;
typedef unsigned long long ull;
typedef __attribute__((ext_vector_type(8))) _Float16 f16x8;
typedef __attribute__((ext_vector_type(4))) float f32x4;
typedef __attribute__((ext_vector_type(4))) int i32x4;

__device__ __forceinline__ float sigm(float x) { return 1.0f / (1.0f + __expf(-x)); }
__device__ __forceinline__ float tanh_f(float x) { return __builtin_fmaf(2.f, sigm(2.f * x), -1.f); }
// 8-f16-granule swizzle within 64-col tiles (bits 3..5 ^= row&7) — involution
__device__ __forceinline__ int swz(int kd, int r) {
    return (kd & ~56) | ((((kd >> 3) & 7) ^ (r & 7)) << 3);
}

__device__ __forceinline__ void gld16(const void* g, void* l) {
    __builtin_amdgcn_global_load_lds(
        (const __attribute__((address_space(1))) unsigned*)g,
        (__attribute__((address_space(3))) unsigned*)l, 16, 0, 0);
}
__device__ __forceinline__ ull ldA(const void* p) {
    return __hip_atomic_load((const ull*)p, __ATOMIC_RELAXED, __HIP_MEMORY_SCOPE_AGENT);
}
__device__ __forceinline__ void stA(void* p, ull v) {
    __hip_atomic_store((ull*)p, v, __ATOMIC_RELAXED, __HIP_MEMORY_SCOPE_AGENT);
}
__device__ __forceinline__ f16x8 mkfrag(ull a, ull b) {
    union { ull u[2]; f16x8 v; } x; x.u[0] = a; x.u[1] = b; return x.v;
}
__device__ __forceinline__ f16x8 asfrag(i32x4 a) {
    union { i32x4 u; f16x8 v; } x; x.u = a; return x.v;
}

// ---------------------------------------------------------------------------
// prep: x -> fp16 plain; ehh/wsm/eih/zw -> fp16 gate-interleaved SWIZZLED
// (LDS paths); dhh -> plain (dec step-0 register path); biases; h0; flags.
// ---------------------------------------------------------------------------
__global__ __launch_bounds__(256) void prep_kernel(
    const float* __restrict__ x,
    const float* __restrict__ enc_W_ih, const float* __restrict__ enc_W_hh,
    const float* __restrict__ enc_b_ih, const float* __restrict__ enc_b_hh,
    const float* __restrict__ dec_W_ih, const float* __restrict__ dec_W_hh,
    const float* __restrict__ dec_b_ih, const float* __restrict__ dec_b_hh,
    const float* __restrict__ z_W,
    f16* __restrict__ x16,   f16* __restrict__ eih_s, f16* __restrict__ ehh_s,
    f16* __restrict__ dhh_p, f16* __restrict__ wsm_s, f16* __restrict__ zw_s,
    float* __restrict__ encB, float* __restrict__ decB, float* __restrict__ decB0,
    f16* __restrict__ hb0, unsigned* __restrict__ flags)
{
    const int tid = blockIdx.x * 256 + threadIdx.x;   // 512 blocks
    const int NT  = 512 * 256;

    for (int i = tid; i < 32768; i += NT) flags[i] = 0;
    for (int i = tid; i < Bsz * Hsz; i += NT) hb0[i] = (f16)0.1f;

    // x16 = (f16)x, plain [B][T][E]
    for (int i = tid; i < (Bsz * Tsz * Esz) / 4; i += NT) {
        const float4 v = *(const float4*)(x + 4 * (size_t)i);
        f16 o[4] = {(f16)v.x, (f16)v.y, (f16)v.z, (f16)v.w};
        ull pk; __builtin_memcpy(&pk, o, 8);
        *(ull*)&x16[4 * (size_t)i] = pk;
    }
    // enc W_ih: [NG][E], swizzled
    for (int i = tid; i < NG * Esz; i += NT) {
        const int n = i >> 8, kd = i & 255;
        const int sr = (n & 3) * Hsz + (n >> 2);
        eih_s[i] = (f16)enc_W_ih[sr * Esz + swz(kd, n)];
    }
    // [NG][H] family
    for (int i = tid; i < NG * Hsz; i += NT) {
        const int n = i >> 9, kd = i & 511;
        const int sr = (n & 3) * Hsz + (n >> 2);
        const int ks = swz(kd, n);
        ehh_s[i] = (f16)enc_W_hh[sr * Hsz + ks];
        wsm_s[i] = (f16)(dec_W_ih[sr * Hsz + ks] + dec_W_hh[sr * Hsz + ks]);
        dhh_p[i] = (f16)dec_W_hh[sr * Hsz + kd];          // plain
    }
    // z_W: [Z][H], swizzled
    for (int i = tid; i < Zsz * Hsz; i += NT) {
        const int n = i >> 9, kd = i & 511;
        zw_s[i] = (f16)z_W[n * Hsz + swz(kd, n)];
    }

    const int wave = tid >> 6, lane = tid & 63;   // 2048 waves exactly
    if (wave < NG) {
        const int sr = (wave & 3) * Hsz + (wave >> 2);
        float s = 0.f;
        for (int k = lane; k < Hsz; k += 64) s += dec_W_ih[sr * Hsz + k];
        for (int off = 32; off; off >>= 1) s += __shfl_down(s, off);
        if (lane == 0) {
            encB[wave] = enc_b_ih[sr] + enc_b_hh[sr];
            const float bi = dec_b_ih[sr] + dec_b_hh[sr];
            decB[wave]  = bi;
            decB0[wave] = bi + 0.1f * s;
        }
    }
}

// ---------------------------------------------------------------------------
// Persistent phase. 256 blocks; group bx=bid&7 owns rows [bx*64,+64);
// ny=bid>>3 owns gate cols [ny*64,+64). 4 waves/block; per-WAVE relaxed
// flags; B read-only in LDS -> no block barriers in the step loop.
// ---------------------------------------------------------------------------
template <bool ENC>
__global__ __launch_bounds__(256, 1) void persist_kernel(
    const f16* __restrict__ x16,     // [B][T][E] plain         (ENC)
    const f16* __restrict__ WihS,    // [NG][E] swizzled        (ENC)
    const f16* __restrict__ BhS,     // [NG][H] swizzled: ehh_s / wsm_s
    const f16* __restrict__ DhhP,    // [NG][H] plain           (DEC step 0)
    const float* __restrict__ biasA, const float* __restrict__ biasB,
    f16* __restrict__ hb0, f16* __restrict__ hb1,
    float* __restrict__ cbuf, f16* __restrict__ Hall,
    unsigned* __restrict__ flags)    // [8 groups][128 waves][16]
{
    __shared__ __align__(16) f16 Bh[8 * 4096];          // h-part weights, 64KB
    __shared__ __align__(16) f16 Wih[ENC ? 4 * 4096 : 8];
    __shared__ __align__(16) float xch[4][4 * 272];     // gate exchange
    __shared__ __align__(16) f16 hx[4][256];            // h repack

    const int tid = threadIdx.x, bid = blockIdx.x;
    const int bx = bid & 7, ny = bid >> 3;
    const int b0 = bx * 64, n0 = ny * 64;
    const int lane = tid & 63, w = tid >> 6;
    const int lr = lane & 15, lkb = lane >> 4;
    const int wm = (w & 1) * 32, wn = (w >> 1) * 32;
    const int rl = lane >> 3, kc = (lane & 7) * 8;

    // ---- one-time init: stage B tiles into LDS ----
#pragma unroll
    for (int kt = 0; kt < 8; ++kt)
#pragma unroll
        for (int s2 = 0; s2 < 2; ++s2) {
            const int g = w + s2 * 4, row = g * 8 + rl;
            gld16(BhS + (size_t)(n0 + row) * Hsz + kt * 64 + kc, &Bh[kt * 4096 + g * 512]);
        }
    if (ENC) {
#pragma unroll
        for (int kt = 0; kt < 4; ++kt)
#pragma unroll
            for (int s2 = 0; s2 < 2; ++s2) {
                const int g = w + s2 * 4, row = g * 8 + rl;
                gld16(WihS + (size_t)(n0 + row) * Esz + kt * 64 + kc, &Wih[kt * 4096 + g * 512]);
            }
    }

    float bvA[2], bvB[2];
#pragma unroll
    for (int j = 0; j < 2; ++j) {
        bvA[j] = biasA[n0 + wn + j * 16 + lr];
        bvB[j] = ENC ? 0.f : biasB[n0 + wn + j * 16 + lr];
    }
    float c_frag[2][2];
#pragma unroll
    for (int i = 0; i < 2; ++i)
#pragma unroll
        for (int j = 0; j < 2; ++j)
            c_frag[i][j] = ENC ? 0.1f
                : cbuf[(size_t)(b0 + wm + i * 16 + lr) * Hsz + ((n0 + wn + j * 16) >> 2) + lkb];

    asm volatile("s_waitcnt vmcnt(0)" ::: "memory");
    __syncthreads();   // B tiles visible to all waves; last barrier of the kernel

    unsigned* gf   = flags + bx * (128 * 16);
    unsigned* self = gf + (ny * 4 + w) * 16;
    // lane polls ONE producer-wave flag (64 producers of our row half)
    const unsigned* myf = gf + (((lane >> 1) * 4 + (w & 1) + ((lane & 1) << 1)) * 16);

    float* xc  = &xch[w][0];
    f16*  hxw = &hx[w][0];

    for (int t = 0; t < Tsz; ++t) {
        const f16* hsrc = (t & 1) ? hb1 : hb0;
        f16*       hdst = (t & 1) ? hb0 : hb1;

        f32x4 acc[2][2];
#pragma unroll
        for (int j = 0; j < 2; ++j) {
            const float bv = (!ENC && t == 0) ? bvB[j] : bvA[j];
            acc[0][j] = (f32x4){bv, bv, bv, bv};
            acc[1][j] = acc[0][j];
        }

        // ---- enc: x A-frags + x-part MFMA BEFORE the wait (independent of h)
        if (ENC) {
            i32x4 ax[2][8];
#pragma unroll
            for (int i = 0; i < 2; ++i)
#pragma unroll
                for (int s = 0; s < 8; ++s)
                    ax[i][s] = *(const i32x4*)(x16 +
                        ((size_t)(b0 + wm + i * 16 + lr) * Tsz + t) * Esz + s * 32 + lkb * 8);
#pragma unroll
            for (int s = 0; s < 8; ++s) {
                f16x8 bq[2];
#pragma unroll
                for (int j = 0; j < 2; ++j) {
                    const int rb = wn + j * 16 + lr;
                    bq[j] = *(const f16x8*)&Wih[(s >> 1) * 4096 + rb * 64 +
                                                ((((s & 1) * 4 + lkb) ^ (rb & 7)) * 8)];
                }
#pragma unroll
                for (int i = 0; i < 2; ++i)
#pragma unroll
                    for (int j = 0; j < 2; ++j)
                        acc[i][j] = __builtin_amdgcn_mfma_f32_16x16x32_f16(
                            asfrag(ax[i][s]), bq[j], acc[i][j], 0, 0, 0);
            }
        }

        // ---- wait for previous step's producers (relaxed poll) ----
        if (t > 0) {
            const unsigned tgt = (unsigned)t;
            while (__hip_atomic_load(myf, __ATOMIC_RELAXED, __HIP_MEMORY_SCOPE_AGENT) < tgt)
                __builtin_amdgcn_s_sleep(1);
            asm volatile("" ::: "memory");
        }

        // ---- h A-frags: global -> registers ----
        ull ah[2][16][2];
#pragma unroll
        for (int i = 0; i < 2; ++i)
#pragma unroll
            for (int s = 0; s < 16; ++s) {
                const f16* p = hsrc + (size_t)(b0 + wm + i * 16 + lr) * Hsz + s * 32 + lkb * 8;
                ah[i][s][0] = ldA(p);
                ah[i][s][1] = ldA(p + 4);
            }

        // ---- h-part MFMA: B from LDS (or global dhh at dec step 0) ----
        if (!ENC && t == 0) {
#pragma unroll
            for (int s = 0; s < 16; ++s) {
                f16x8 bq[2];
#pragma unroll
                for (int j = 0; j < 2; ++j)
                    bq[j] = *(const f16x8*)&DhhP[
                        (size_t)(n0 + wn + j * 16 + lr) * Hsz + s * 32 + lkb * 8];
#pragma unroll
                for (int i = 0; i < 2; ++i)
                    { const f16x8 af = mkfrag(ah[i][s][0], ah[i][s][1]);
#pragma unroll
                      for (int j = 0; j < 2; ++j)
                        acc[i][j] = __builtin_amdgcn_mfma_f32_16x16x32_f16(
                            af, bq[j], acc[i][j], 0, 0, 0); }
            }
        } else {
#pragma unroll
            for (int s = 0; s < 16; ++s) {
                f16x8 bq[2];
#pragma unroll
                for (int j = 0; j < 2; ++j) {
                    const int rb = wn + j * 16 + lr;
                    bq[j] = *(const f16x8*)&Bh[(s >> 1) * 4096 + rb * 64 +
                                               ((((s & 1) * 4 + lkb) ^ (rb & 7)) * 8)];
                }
#pragma unroll
                for (int i = 0; i < 2; ++i)
                    { const f16x8 af = mkfrag(ah[i][s][0], ah[i][s][1]);
#pragma unroll
                      for (int j = 0; j < 2; ++j)
                        acc[i][j] = __builtin_amdgcn_mfma_f32_16x16x32_f16(
                            af, bq[j], acc[i][j], 0, 0, 0); }
            }
        }

        // ---- wave-local gate transpose (batched, one LDS round trip) ----
#pragma unroll
        for (int i = 0; i < 2; ++i)
#pragma unroll
            for (int j = 0; j < 2; ++j)
#pragma unroll
                for (int r = 0; r < 4; ++r)
                    xc[(i * 2 + j) * 272 + lr * 17 + lkb * 4 + r] = acc[i][j][r];
        asm volatile("s_waitcnt lgkmcnt(0)" ::: "memory");

#pragma unroll
        for (int i = 0; i < 2; ++i)
#pragma unroll
            for (int j = 0; j < 2; ++j) {
                const float gi = xc[(i * 2 + j) * 272 + (4 * lkb + 0) * 17 + lr];
                const float gf = xc[(i * 2 + j) * 272 + (4 * lkb + 1) * 17 + lr];
                const float gg = xc[(i * 2 + j) * 272 + (4 * lkb + 2) * 17 + lr];
                const float go = xc[(i * 2 + j) * 272 + (4 * lkb + 3) * 17 + lr];
                const float iv = sigm(gi), fv = sigm(gf);
                const float gv = tanh_f(gg), ov = sigm(go);
                const float cn = fv * c_frag[i][j] + iv * gv;
                c_frag[i][j] = cn;
                hxw[(i * 16 + lr) * 8 + j * 4 + lkb] = (f16)(ov * tanh_f(cn));
            }
        asm volatile("s_waitcnt lgkmcnt(0)" ::: "memory");

        // ---- pack + h store (16B per lane, lanes 0..31) ----
        ull lo = 0, hi = 0;
        const int hrow = b0 + wm + (lane & 31);
        const int cb = (n0 + wn) >> 2;
        if (lane < 32) {
            lo = *(const ull*)&hxw[(lane & 31) * 8];
            hi = *(const ull*)&hxw[(lane & 31) * 8 + 4];
            f16* dp = hdst + (size_t)hrow * Hsz + cb;
            stA(dp, lo);
            stA(dp + 4, hi);
        }

        // ---- drain own stores, then relaxed flag signal ----
        asm volatile("s_waitcnt vmcnt(0)" ::: "memory");
        if (t < Tsz - 1 && lane == 0)
            __hip_atomic_store(self, (unsigned)(t + 1),
                               __ATOMIC_RELAXED, __HIP_MEMORY_SCOPE_AGENT);

        // ---- Hall store off the critical path ----
        if (!ENC && lane < 32) {
            f16* hp = Hall + ((size_t)hrow * Tsz + t) * Hsz + swz(cb, t);
            *(ull*)hp = lo;
            *(ull*)(hp + 4) = hi;
        }
    }

    if (ENC) {
#pragma unroll
        for (int i = 0; i < 2; ++i)
#pragma unroll
            for (int j = 0; j < 2; ++j)
                cbuf[(size_t)(b0 + wm + i * 16 + lr) * Hsz + ((n0 + wn + j * 16) >> 2) + lkb]
                    = c_frag[i][j];
    }
}

// ---------------------------------------------------------------------------
// final z projection: out[m][col] = tanh(Hall[m] @ zW^T + zb), m = b*T + t
// ---------------------------------------------------------------------------
__global__ __launch_bounds__(256, 2) void z_final(
    const f16* __restrict__ Hall, const f16* __restrict__ zw,
    const float* __restrict__ zb, float* __restrict__ out)
{
    __shared__ f16 As[2][4096];
    __shared__ f16 Bs[2][4096];

    const int tid = threadIdx.x;
    const int lane = tid & 63, w = tid >> 6;
    const int lr = lane & 15, lkb = lane >> 4;
    const int wm = (w & 1) * 32, wn = (w >> 1) * 32;
    const int m0 = blockIdx.x * 64;
    const int n0 = blockIdx.y * 64;
    const int rl = lane >> 3, kc = (lane & 7) * 8;

    f32x4 acc[2][2];
#pragma unroll
    for (int j = 0; j < 2; ++j) {
        const float bv = zb[n0 + wn + j * 16 + lr];
        acc[0][j] = (f32x4){bv, bv, bv, bv};
        acc[1][j] = acc[0][j];
    }

    auto stage = [&](int buf, int kt) {
#pragma unroll
        for (int s = 0; s < 2; ++s) {
            const int g = w + s * 4, row = g * 8 + rl;
            gld16(Hall + (size_t)(m0 + row) * Hsz + kt * 64 + kc, &As[buf][g * 512]);
            gld16(zw   + (size_t)(n0 + row) * Hsz + kt * 64 + kc, &Bs[buf][g * 512]);
        }
    };

    stage(0, 0);
    int cur = 0;
    for (int kt = 0; kt < 8; ++kt) {
        asm volatile("s_waitcnt vmcnt(0)" ::: "memory");
        __syncthreads();
        if (kt + 1 < 8) stage(cur ^ 1, kt + 1);
        f16x8 af[2][2], bf[2][2];
#pragma unroll
        for (int i = 0; i < 2; ++i) {
            const int ra = wm + i * 16 + lr;
            const int rb = wn + i * 16 + lr;
#pragma unroll
            for (int ks = 0; ks < 2; ++ks) {
                af[i][ks] = *(const f16x8*)&As[cur][ra * 64 + (((ks * 4 + lkb) ^ (ra & 7)) * 8)];
                bf[i][ks] = *(const f16x8*)&Bs[cur][rb * 64 + (((ks * 4 + lkb) ^ (rb & 7)) * 8)];
            }
        }
#pragma unroll
        for (int ks = 0; ks < 2; ++ks)
#pragma unroll
            for (int i = 0; i < 2; ++i)
#pragma unroll
                for (int j = 0; j < 2; ++j)
                    acc[i][j] = __builtin_amdgcn_mfma_f32_16x16x32_f16(
                        af[i][ks], bf[j][ks], acc[i][j], 0, 0, 0);
        cur ^= 1;
    }
#pragma unroll
    for (int i = 0; i < 2; ++i)
#pragma unroll
        for (int j = 0; j < 2; ++j)
#pragma unroll
            for (int r = 0; r < 4; ++r) {
                const int m = m0 + wm + i * 16 + lkb * 4 + r;
                const int col = n0 + wn + j * 16 + lr;
                out[(size_t)m * Zsz + col] = tanh_f(acc[i][j][r]);
            }
}

// ---------------------------------------------------------------------------
extern "C" void kernel_launch(void* const* d_in, const int* in_sizes, int n_in,
                              void* d_out, int out_size, void* d_ws, size_t ws_size,
                              hipStream_t stream) {
    (void)in_sizes; (void)n_in; (void)out_size; (void)ws_size;
    const float* x        = (const float*)d_in[0];
    const float* enc_W_ih = (const float*)d_in[1];
    const float* enc_W_hh = (const float*)d_in[2];
    const float* enc_b_ih = (const float*)d_in[3];
    const float* enc_b_hh = (const float*)d_in[4];
    const float* dec_W_ih = (const float*)d_in[5];
    const float* dec_W_hh = (const float*)d_in[6];
    const float* dec_b_ih = (const float*)d_in[7];
    const float* dec_b_hh = (const float*)d_in[8];
    const float* z_W      = (const float*)d_in[9];
    const float* z_b      = (const float*)d_in[10];
    float* out = (float*)d_out;

    unsigned* flags = (unsigned*)d_ws;               // 32768 u32: enc [0..16383], dec [16384..]
    float* fp    = (float*)(flags + 32768);
    float* encB  = fp;  fp += NG;
    float* decB  = fp;  fp += NG;
    float* decB0 = fp;  fp += NG;
    float* cbuf  = fp;  fp += Bsz * Hsz;
    f16* hp    = (f16*)fp;
    f16* hb0   = hp;  hp += Bsz * Hsz;
    f16* hb1   = hp;  hp += Bsz * Hsz;
    f16* x16   = hp;  hp += (size_t)Bsz * Tsz * Esz;
    f16* eih_s = hp;  hp += (size_t)NG * Esz;
    f16* ehh_s = hp;  hp += (size_t)NG * Hsz;
    f16* dhh_p = hp;  hp += (size_t)NG * Hsz;
    f16* wsm_s = hp;  hp += (size_t)NG * Hsz;
    f16* zw_s  = hp;  hp += (size_t)Zsz * Hsz;
    f16* Hall  = hp;  hp += (size_t)Bsz * Tsz * Hsz;

    prep_kernel<<<512, 256, 0, stream>>>(
        x, enc_W_ih, enc_W_hh, enc_b_ih, enc_b_hh,
        dec_W_ih, dec_W_hh, dec_b_ih, dec_b_hh, z_W,
        x16, eih_s, ehh_s, dhh_p, wsm_s, zw_s,
        encB, decB, decB0, hb0, flags);

    persist_kernel<true><<<256, 256, 0, stream>>>(
        x16, eih_s, ehh_s, nullptr, encB, nullptr,
        hb0, hb1, cbuf, nullptr, flags);

    persist_kernel<false><<<256, 256, 0, stream>>>(
        nullptr, nullptr, wsm_s, dhh_p, decB, decB0,
        hb0, hb1, cbuf, Hall, flags + 16384);

    z_final<<<dim3(1024, 4), 256, 0, stream>>>(Hall, zw_s, z_b, out);
}

// Round 9
// 1593.582 us; speedup vs baseline: 5.0795x; 1.8082x over previous
//
#include <hip/hip_runtime.h>

// Multi-launch LSTM autoencoder, R9.
// Per-step kernels (graph-captured), but with the persistent-kernel data path:
// - B weights: LDS via gld16, staged once per launch, ONE barrier, no k-loop syncs
// - A (h, x): global->register fragments; h/x in tile-packed layouts for
//   fully-coalesced stores/loads
// - c: thread-private flat global (identical mapping every launch)
// - cross-step visibility via kernel-boundary coherence (no spins -> no hangs)

#define Bsz 512
#define Tsz 128
#define Esz 256
#define Hsz 512
#define Zsz 256
#define NG  2048   // 4*Hsz gate columns, interleaved n = 4*j + gate

typedef _Float16 f16;
typedef unsigned long long ull;
typedef __attribute__((ext_vector_type(8))) _Float16 f16x8;
typedef __attribute__((ext_vector_type(4))) float f32x4;
typedef __attribute__((ext_vector_type(4))) int i32x4;

__device__ __forceinline__ float sigm(float x) { return 1.0f / (1.0f + __expf(-x)); }
__device__ __forceinline__ float tanh_f(float x) { return __builtin_fmaf(2.f, sigm(2.f * x), -1.f); }
// 8-f16-granule swizzle within 64-col tiles (bits 3..5 ^= r&7) — involution
__device__ __forceinline__ int swz(int kd, int r) {
    return (kd & ~56) | ((((kd >> 3) & 7) ^ (r & 7)) << 3);
}
__device__ __forceinline__ void gld16(const void* g, void* l) {
    __builtin_amdgcn_global_load_lds(
        (const __attribute__((address_space(1))) unsigned*)g,
        (__attribute__((address_space(3))) unsigned*)l, 16, 0, 0);
}
__device__ __forceinline__ f16x8 asfrag(i32x4 a) {
    union { i32x4 u; f16x8 v; } x; x.u = a; return x.v;
}

// ---------------------------------------------------------------------------
// prep: x -> tile-packed fp16 x_ex[t][g][b][8]; weights -> fp16 gate-
// interleaved + swizzled; biases; h0 tile buffer; c flat init.
// ---------------------------------------------------------------------------
__global__ __launch_bounds__(256) void prep_kernel(
    const float* __restrict__ x,
    const float* __restrict__ enc_W_ih, const float* __restrict__ enc_W_hh,
    const float* __restrict__ enc_b_ih, const float* __restrict__ enc_b_hh,
    const float* __restrict__ dec_W_ih, const float* __restrict__ dec_W_hh,
    const float* __restrict__ dec_b_ih, const float* __restrict__ dec_b_hh,
    const float* __restrict__ z_W,
    f16* __restrict__ xe,    f16* __restrict__ eih_s, f16* __restrict__ ehh_s,
    f16* __restrict__ dhh_s, f16* __restrict__ wsm_s, f16* __restrict__ zw_s,
    float* __restrict__ encB, float* __restrict__ decB, float* __restrict__ decB0,
    f16* __restrict__ hb0, float* __restrict__ cflat)
{
    const int tid = blockIdx.x * 256 + threadIdx.x;   // 512 blocks
    const int NT  = 512 * 256;

    for (int i = tid; i < Bsz * Hsz; i += NT) hb0[i] = (f16)0.1f;      // tile layout-agnostic
    for (int i = tid; i < 256 * 256 * 4; i += NT) cflat[i] = 0.1f;

    // xe[((t*32 + g)*512 + b)*8 + e] = x[b][t][g*8 + e]
    for (int i = tid; i < Bsz * Tsz * Esz; i += NT) {
        const int e = i & 7, b = (i >> 3) & 511, g = (i >> 12) & 31, t = i >> 17;
        xe[i] = (f16)x[((size_t)b * Tsz + t) * Esz + g * 8 + e];
    }
    // enc W_ih: [NG][E], swizzled
    for (int i = tid; i < NG * Esz; i += NT) {
        const int n = i >> 8, kd = i & 255;
        const int sr = (n & 3) * Hsz + (n >> 2);
        eih_s[i] = (f16)enc_W_ih[sr * Esz + swz(kd, n)];
    }
    // [NG][H] family, swizzled
    for (int i = tid; i < NG * Hsz; i += NT) {
        const int n = i >> 9, kd = i & 511;
        const int sr = (n & 3) * Hsz + (n >> 2);
        const int ks = swz(kd, n);
        ehh_s[i] = (f16)enc_W_hh[sr * Hsz + ks];
        const float dv = dec_W_hh[sr * Hsz + ks];
        dhh_s[i] = (f16)dv;
        wsm_s[i] = (f16)(dec_W_ih[sr * Hsz + ks] + dv);
    }
    // z_W: [Z][H], swizzled
    for (int i = tid; i < Zsz * Hsz; i += NT) {
        const int n = i >> 9, kd = i & 511;
        zw_s[i] = (f16)z_W[n * Hsz + swz(kd, n)];
    }

    const int wave = tid >> 6, lane = tid & 63;   // 2048 waves exactly
    if (wave < NG) {
        const int sr = (wave & 3) * Hsz + (wave >> 2);
        float s = 0.f;
        for (int k = lane; k < Hsz; k += 64) s += dec_W_ih[sr * Hsz + k];
        for (int off = 32; off; off >>= 1) s += __shfl_down(s, off);
        if (lane == 0) {
            encB[wave] = enc_b_ih[sr] + enc_b_hh[sr];
            const float bi = dec_b_ih[sr] + dec_b_hh[sr];
            decB[wave]  = bi;
            decB0[wave] = bi + 0.1f * s;
        }
    }
}

// ---------------------------------------------------------------------------
// One LSTM step. grid (8, 32), 256 thr. h buffers in tile layout:
// h[g][512][8] f16, g = hcol/8. No k-loop barriers.
// ---------------------------------------------------------------------------
template <bool ENC>
__global__ __launch_bounds__(256, 1) void lstm_step(
    int t,
    const f16* __restrict__ xe,     // x_ex                    (ENC)
    const f16* __restrict__ BX,     // eih_s [NG][E] swizzled  (ENC)
    const f16* __restrict__ BH,     // ehh_s / wsm_s / dhh_s [NG][H] swizzled
    const float* __restrict__ biasI,
    const f16* __restrict__ hsrc, f16* __restrict__ hdst,   // tile layout
    float* __restrict__ cflat, f16* __restrict__ Hall)      // Hall: DEC only
{
    constexpr int KT = ENC ? 12 : 8;
    __shared__ __align__(16) f16 Bs[KT * 4096];
    __shared__ __align__(16) float xch[4][4 * 272];
    __shared__ __align__(16) f16 hx[4][256];

    const int tid = threadIdx.x;
    const int bx = blockIdx.x, ny = blockIdx.y;
    const int b0 = bx * 64, n0 = ny * 64;
    const int lane = tid & 63, w = tid >> 6;
    const int lr = lane & 15, lkb = lane >> 4;
    const int wm = (w & 1) * 32, wn = (w >> 1) * 32;
    const int rl = lane >> 3, kc = (lane & 7) * 8;

    // ---- issue B staging (gld16, wave-uniform dst + lane*16) ----
    if (ENC) {
#pragma unroll
        for (int kt = 0; kt < 4; ++kt)
#pragma unroll
            for (int s2 = 0; s2 < 2; ++s2) {
                const int g = w + s2 * 4, row = g * 8 + rl;
                gld16(BX + (size_t)(n0 + row) * Esz + kt * 64 + kc, &Bs[kt * 4096 + g * 512]);
            }
#pragma unroll
        for (int kt = 0; kt < 8; ++kt)
#pragma unroll
            for (int s2 = 0; s2 < 2; ++s2) {
                const int g = w + s2 * 4, row = g * 8 + rl;
                gld16(BH + (size_t)(n0 + row) * Hsz + kt * 64 + kc, &Bs[(4 + kt) * 4096 + g * 512]);
            }
    } else {
#pragma unroll
        for (int kt = 0; kt < 8; ++kt)
#pragma unroll
            for (int s2 = 0; s2 < 2; ++s2) {
                const int g = w + s2 * 4, row = g * 8 + rl;
                gld16(BH + (size_t)(n0 + row) * Hsz + kt * 64 + kc, &Bs[kt * 4096 + g * 512]);
            }
    }

    // ---- issue c load (thread-private, coalesced) ----
    const size_t cbase = (((size_t)ny * 8 + bx) * 256 + tid) * 4;
    float4 cc = *(const float4*)&cflat[cbase];

    // ---- issue A-fragment loads ----
    i32x4 ax[2][8];
    if (ENC) {
#pragma unroll
        for (int i = 0; i < 2; ++i)
#pragma unroll
            for (int s = 0; s < 8; ++s)
                ax[i][s] = *(const i32x4*)(xe +
                    (((size_t)(t * 32 + s * 4 + lkb)) * 512 + b0 + wm + i * 16 + lr) * 8);
    }
    i32x4 ah[2][16];
#pragma unroll
    for (int i = 0; i < 2; ++i)
#pragma unroll
        for (int s = 0; s < 16; ++s)
            ah[i][s] = *(const i32x4*)(hsrc +
                (((size_t)(s * 4 + lkb)) * 512 + b0 + wm + i * 16 + lr) * 8);

    asm volatile("s_waitcnt vmcnt(0)" ::: "memory");
    __syncthreads();   // Bs visible; the only block barrier

    // ---- accumulators (bias folded; host picks decB0 for dec t=0) ----
    f32x4 acc[2][2];
#pragma unroll
    for (int j = 0; j < 2; ++j) {
        const float bv = biasI[n0 + wn + j * 16 + lr];
        acc[0][j] = (f32x4){bv, bv, bv, bv};
        acc[1][j] = acc[0][j];
    }

    // ---- K loop: 2*KT slices of 32, no barriers ----
#pragma unroll
    for (int s = 0; s < 2 * KT; ++s) {
        const int kt = s >> 1;
        f16x8 bq[2];
#pragma unroll
        for (int j = 0; j < 2; ++j) {
            const int rb = wn + j * 16 + lr;
            bq[j] = *(const f16x8*)&Bs[kt * 4096 + rb * 64 + ((((s & 1) * 4 + lkb) ^ (rb & 7)) * 8)];
        }
#pragma unroll
        for (int i = 0; i < 2; ++i) {
            const f16x8 af = ENC ? (s < 8 ? asfrag(ax[i][s]) : asfrag(ah[i][s - 8]))
                                 : asfrag(ah[i][s]);
#pragma unroll
            for (int j = 0; j < 2; ++j)
                acc[i][j] = __builtin_amdgcn_mfma_f32_16x16x32_f16(af, bq[j], acc[i][j], 0, 0, 0);
        }
    }

    // ---- wave-local gate transpose (lgkmcnt only) ----
    float* xc = &xch[w][0];
    f16*  hxw = &hx[w][0];
#pragma unroll
    for (int i = 0; i < 2; ++i)
#pragma unroll
        for (int j = 0; j < 2; ++j)
#pragma unroll
            for (int r = 0; r < 4; ++r)
                xc[(i * 2 + j) * 272 + lr * 17 + lkb * 4 + r] = acc[i][j][r];
    asm volatile("s_waitcnt lgkmcnt(0)" ::: "memory");

#pragma unroll
    for (int i = 0; i < 2; ++i)
#pragma unroll
        for (int j = 0; j < 2; ++j) {
            const float gi = xc[(i * 2 + j) * 272 + (4 * lkb + 0) * 17 + lr];
            const float gf = xc[(i * 2 + j) * 272 + (4 * lkb + 1) * 17 + lr];
            const float gg = xc[(i * 2 + j) * 272 + (4 * lkb + 2) * 17 + lr];
            const float go = xc[(i * 2 + j) * 272 + (4 * lkb + 3) * 17 + lr];
            const float iv = sigm(gi), fv = sigm(gf);
            const float gv = tanh_f(gg), ov = sigm(go);
            const int q = i * 2 + j;
            const float cn = fv * cc[q] + iv * gv;
            cc[q] = cn;
            hxw[(i * 16 + lr) * 8 + j * 4 + lkb] = (f16)(ov * tanh_f(cn));
        }
    asm volatile("s_waitcnt lgkmcnt(0)" ::: "memory");

    // ---- c store (coalesced 16B) ----
    *(float4*)&cflat[cbase] = cc;

    // ---- h store: tile layout, 16B/lane fully contiguous per wave ----
    if (lane < 32) {
        const int g = ny * 2 + (w >> 1);
        const int row = b0 + wm + (lane & 31);
        const i32x4 hv = *(const i32x4*)&hxw[(lane & 31) * 8];
        *(i32x4*)(hdst + ((size_t)g * 512 + row) * 8) = hv;
        if (!ENC) {
            const int cb = g * 8;
            *(i32x4*)(Hall + ((size_t)row * Tsz + t) * Hsz + swz(cb, t)) = hv;
        }
    }
}

// ---------------------------------------------------------------------------
// final z projection: out[m][col] = tanh(Hall[m] @ zW^T + zb), m = b*T + t
// ---------------------------------------------------------------------------
__global__ __launch_bounds__(256, 2) void z_final(
    const f16* __restrict__ Hall, const f16* __restrict__ zw,
    const float* __restrict__ zb, float* __restrict__ out)
{
    __shared__ f16 As[2][4096];
    __shared__ f16 Bs[2][4096];

    const int tid = threadIdx.x;
    const int lane = tid & 63, w = tid >> 6;
    const int lr = lane & 15, lkb = lane >> 4;
    const int wm = (w & 1) * 32, wn = (w >> 1) * 32;
    const int m0 = blockIdx.x * 64;
    const int n0 = blockIdx.y * 64;
    const int rl = lane >> 3, kc = (lane & 7) * 8;

    f32x4 acc[2][2];
#pragma unroll
    for (int j = 0; j < 2; ++j) {
        const float bv = zb[n0 + wn + j * 16 + lr];
        acc[0][j] = (f32x4){bv, bv, bv, bv};
        acc[1][j] = acc[0][j];
    }

    auto stage = [&](int buf, int kt) {
#pragma unroll
        for (int s = 0; s < 2; ++s) {
            const int g = w + s * 4, row = g * 8 + rl;
            gld16(Hall + (size_t)(m0 + row) * Hsz + kt * 64 + kc, &As[buf][g * 512]);
            gld16(zw   + (size_t)(n0 + row) * Hsz + kt * 64 + kc, &Bs[buf][g * 512]);
        }
    };

    stage(0, 0);
    int cur = 0;
    for (int kt = 0; kt < 8; ++kt) {
        asm volatile("s_waitcnt vmcnt(0)" ::: "memory");
        __syncthreads();
        if (kt + 1 < 8) stage(cur ^ 1, kt + 1);
        f16x8 af[2][2], bf[2][2];
#pragma unroll
        for (int i = 0; i < 2; ++i) {
            const int ra = wm + i * 16 + lr;
            const int rb = wn + i * 16 + lr;
#pragma unroll
            for (int ks = 0; ks < 2; ++ks) {
                af[i][ks] = *(const f16x8*)&As[cur][ra * 64 + (((ks * 4 + lkb) ^ (ra & 7)) * 8)];
                bf[i][ks] = *(const f16x8*)&Bs[cur][rb * 64 + (((ks * 4 + lkb) ^ (rb & 7)) * 8)];
            }
        }
#pragma unroll
        for (int ks = 0; ks < 2; ++ks)
#pragma unroll
            for (int i = 0; i < 2; ++i)
#pragma unroll
                for (int j = 0; j < 2; ++j)
                    acc[i][j] = __builtin_amdgcn_mfma_f32_16x16x32_f16(
                        af[i][ks], bf[j][ks], acc[i][j], 0, 0, 0);
        cur ^= 1;
    }
#pragma unroll
    for (int i = 0; i < 2; ++i)
#pragma unroll
        for (int j = 0; j < 2; ++j)
#pragma unroll
            for (int r = 0; r < 4; ++r) {
                const int m = m0 + wm + i * 16 + lkb * 4 + r;
                const int col = n0 + wn + j * 16 + lr;
                out[(size_t)m * Zsz + col] = tanh_f(acc[i][j][r]);
            }
}

// ---------------------------------------------------------------------------
extern "C" void kernel_launch(void* const* d_in, const int* in_sizes, int n_in,
                              void* d_out, int out_size, void* d_ws, size_t ws_size,
                              hipStream_t stream) {
    (void)in_sizes; (void)n_in; (void)out_size; (void)ws_size;
    const float* x        = (const float*)d_in[0];
    const float* enc_W_ih = (const float*)d_in[1];
    const float* enc_W_hh = (const float*)d_in[2];
    const float* enc_b_ih = (const float*)d_in[3];
    const float* enc_b_hh = (const float*)d_in[4];
    const float* dec_W_ih = (const float*)d_in[5];
    const float* dec_W_hh = (const float*)d_in[6];
    const float* dec_b_ih = (const float*)d_in[7];
    const float* dec_b_hh = (const float*)d_in[8];
    const float* z_W      = (const float*)d_in[9];
    const float* z_b      = (const float*)d_in[10];
    float* out = (float*)d_out;

    float* fp    = (float*)d_ws;
    float* encB  = fp;  fp += NG;
    float* decB  = fp;  fp += NG;
    float* decB0 = fp;  fp += NG;
    float* cflat = fp;  fp += 256 * 256 * 4;
    f16* hp    = (f16*)fp;
    f16* hb0   = hp;  hp += Bsz * Hsz;
    f16* hb1   = hp;  hp += Bsz * Hsz;
    f16* xe    = hp;  hp += (size_t)Bsz * Tsz * Esz;
    f16* eih_s = hp;  hp += (size_t)NG * Esz;
    f16* ehh_s = hp;  hp += (size_t)NG * Hsz;
    f16* dhh_s = hp;  hp += (size_t)NG * Hsz;
    f16* wsm_s = hp;  hp += (size_t)NG * Hsz;
    f16* zw_s  = hp;  hp += (size_t)Zsz * Hsz;
    f16* Hall  = hp;  hp += (size_t)Bsz * Tsz * Hsz;

    prep_kernel<<<512, 256, 0, stream>>>(
        x, enc_W_ih, enc_W_hh, enc_b_ih, enc_b_hh,
        dec_W_ih, dec_W_hh, dec_b_ih, dec_b_hh, z_W,
        xe, eih_s, ehh_s, dhh_s, wsm_s, zw_s,
        encB, decB, decB0, hb0, cflat);

    f16* hb[2] = {hb0, hb1};
    const dim3 sgrid(8, 32), zgrid(1024, 4);

    // encoder: global step u = t
    for (int t = 0; t < Tsz; ++t)
        lstm_step<true><<<sgrid, 256, 0, stream>>>(
            t, xe, eih_s, ehh_s, encB,
            hb[t & 1], hb[(t + 1) & 1], cflat, nullptr);

    // decoder: global step u = 128 + t (parity continues seamlessly)
    for (int t = 0; t < Tsz; ++t) {
        const int u = Tsz + t;
        lstm_step<false><<<sgrid, 256, 0, stream>>>(
            t, nullptr, nullptr, (t == 0) ? dhh_s : wsm_s,
            (t == 0) ? decB0 : decB,
            hb[u & 1], hb[(u + 1) & 1], cflat, Hall);
    }

    z_final<<<zgrid, 256, 0, stream>>>(Hall, zw_s, z_b, out);
}